// Round 9
// baseline (472.257 us; speedup 1.0000x reference)
//
#include <hip/hip_runtime.h>

#define HEADS 16
#define DH 64
#define SEQ 2048
#define MROWS 4096          // b*n = 2*2048
#define KDIM 1024
#define N3 3072

// e * sqrt(1/1024)
#define C_D (2.718281828459045 * 0.03125)
#define C_F ((float)C_D)
#define QSCALE ((float)(C_D * C_D / 32.0))

typedef __attribute__((ext_vector_type(8))) short bf16x8;
typedef __attribute__((ext_vector_type(4))) short s16x4;
typedef __attribute__((ext_vector_type(4))) float f32x4;
#define MFMA16 __builtin_amdgcn_mfma_f32_16x16x32_bf16

__device__ __forceinline__ unsigned short f2bf(float f) {
  unsigned int u = __float_as_uint(f);
  unsigned int r = u + 0x7FFFu + ((u >> 16) & 1u);  // RNE
  return (unsigned short)(r >> 16);
}
__device__ __forceinline__ float bf2f(unsigned short h) {
  return __uint_as_float(((unsigned int)h) << 16);
}
// hi bf16 in bits [15:0], lo bf16 in bits [31:16]
__device__ __forceinline__ unsigned int split2u(float v) {
  const unsigned short hh = f2bf(v);
  const unsigned short ll = f2bf(v - bf2f(hh));
  return (unsigned int)hh | ((unsigned int)ll << 16);
}

// ---------------------------------------------------------------------------
// signs: s = gate(m) ? sign(w) : 0, in bf16 {±1, 0} (exact)
// ---------------------------------------------------------------------------
__global__ __launch_bounds__(256) void sign_gate(const float* __restrict__ w,
                                                 const float* __restrict__ m,
                                                 unsigned short* __restrict__ s,
                                                 int n4) {
  const int i = blockIdx.x * 256 + threadIdx.x;
  if (i >= n4) return;
  const float4 wv = ((const float4*)w)[i];
  const float4 mv = ((const float4*)m)[i];
  s16x4 r;
  r[0] = (mv.x > 0.f) ? (wv.x > 0.f ? (short)0x3F80 : (short)0xBF80) : (short)0;
  r[1] = (mv.y > 0.f) ? (wv.y > 0.f ? (short)0x3F80 : (short)0xBF80) : (short)0;
  r[2] = (mv.z > 0.f) ? (wv.z > 0.f ? (short)0x3F80 : (short)0xBF80) : (short)0;
  r[3] = (mv.w > 0.f) ? (wv.w > 0.f ? (short)0x3F80 : (short)0xBF80) : (short)0;
  ((s16x4*)s)[i] = r;
}

// ---------------------------------------------------------------------------
// Split-bf16 MFMA GEMM (unchanged this round): C = (A_hi + A_lo) @ Bsgn^T.
// ---------------------------------------------------------------------------
template <int MODE>
__global__ __launch_bounds__(256) void gemm_mfma(
    const float* __restrict__ Af, const unsigned int* __restrict__ Apk,
    const unsigned short* __restrict__ Bsgn, const float* __restrict__ bias,
    const float* __restrict__ bias_m, unsigned int* __restrict__ qpk,
    unsigned short* __restrict__ khg, unsigned short* __restrict__ klg,
    unsigned short* __restrict__ vthg, unsigned short* __restrict__ vtlg,
    float* __restrict__ oo, int M, int N, int K) {
  __shared__ unsigned short Ah[128 * 40];
  __shared__ unsigned short Al[128 * 40];
  __shared__ unsigned short Bt[128 * 40];
  const int tid = threadIdx.x;
  const int l = tid & 63;
  const int w = tid >> 6;
  const int lr = l & 15, lg = l >> 4;
  const int wr = w >> 1, wc = w & 1;
  const int bm = blockIdx.y * 128, bn = blockIdx.x * 128;

  f32x4 acc[4][4];
#pragma unroll
  for (int i = 0; i < 4; ++i)
#pragma unroll
    for (int j = 0; j < 4; ++j)
#pragma unroll
      for (int r = 0; r < 4; ++r) acc[i][j][r] = 0.f;

  for (int k0 = 0; k0 < K; k0 += 32) {
    __syncthreads();
    // ---- stage A (128x32) ----
#pragma unroll
    for (int p = 0; p < 4; ++p) {
      const int ch = tid + p * 256;
      const int r = ch >> 3, c = ch & 7;
      s16x4 hv, lv;
      if (MODE == 0) {
        const float4 f = *(const float4*)&Af[(size_t)(bm + r) * K + k0 + c * 4];
        const unsigned int p0 = split2u(f.x), p1 = split2u(f.y),
                           p2 = split2u(f.z), p3 = split2u(f.w);
        hv[0] = (short)(p0 & 0xFFFFu); lv[0] = (short)(p0 >> 16);
        hv[1] = (short)(p1 & 0xFFFFu); lv[1] = (short)(p1 >> 16);
        hv[2] = (short)(p2 & 0xFFFFu); lv[2] = (short)(p2 >> 16);
        hv[3] = (short)(p3 & 0xFFFFu); lv[3] = (short)(p3 >> 16);
      } else {
        const uint4 u = *(const uint4*)&Apk[(size_t)(bm + r) * K + k0 + c * 4];
        hv[0] = (short)(u.x & 0xFFFFu); lv[0] = (short)(u.x >> 16);
        hv[1] = (short)(u.y & 0xFFFFu); lv[1] = (short)(u.y >> 16);
        hv[2] = (short)(u.z & 0xFFFFu); lv[2] = (short)(u.z >> 16);
        hv[3] = (short)(u.w & 0xFFFFu); lv[3] = (short)(u.w >> 16);
      }
      *(s16x4*)&Ah[r * 40 + c * 4] = hv;
      *(s16x4*)&Al[r * 40 + c * 4] = lv;
    }
    // ---- stage B signs ----
#pragma unroll
    for (int p = 0; p < 2; ++p) {
      const int ch = tid + p * 256;
      const int r = ch >> 2, c = ch & 3;
      const uint4 u = *(const uint4*)&Bsgn[(size_t)(bn + r) * K + k0 + c * 8];
      *(uint4*)&Bt[r * 40 + c * 8] = u;
    }
    __syncthreads();

    bf16x8 af[4], alf[4], bfr[4];
#pragma unroll
    for (int i = 0; i < 4; ++i) {
      const int row = wr * 64 + i * 16 + lr;
      af[i] = *(const bf16x8*)&Ah[row * 40 + lg * 8];
      alf[i] = *(const bf16x8*)&Al[row * 40 + lg * 8];
    }
#pragma unroll
    for (int j = 0; j < 4; ++j)
      bfr[j] = *(const bf16x8*)&Bt[(wc * 64 + j * 16 + lr) * 40 + lg * 8];
#pragma unroll
    for (int i = 0; i < 4; ++i)
#pragma unroll
      for (int j = 0; j < 4; ++j) {
        acc[i][j] = MFMA16(af[i], bfr[j], acc[i][j], 0, 0, 0);
        acc[i][j] = MFMA16(alf[i], bfr[j], acc[i][j], 0, 0, 0);
      }
  }

  // ---- epilogue ----
  if (MODE == 0) {
    const int part = bn >> 10;      // 0=q, 1=k, 2=v
    const int rembase = bn & 1023;  // within part
#pragma unroll
    for (int i = 0; i < 4; ++i)
#pragma unroll
      for (int j = 0; j < 4; ++j) {
        const int gcol = rembase + wc * 64 + j * 16 + lr;
        const int h = gcol >> 6, d = gcol & 63;
#pragma unroll
        for (int r = 0; r < 4; ++r) {
          const int grow = bm + wr * 64 + i * 16 + lg * 4 + r;
          const int b = grow >> 11, n = grow & 2047;
          const int bh = b * HEADS + h;
          const float v = acc[i][j][r];
          if (part == 0) {
            qpk[((size_t)bh * SEQ + n) * DH + d] = split2u(v * QSCALE);
          } else if (part == 1) {
            const unsigned int u = split2u(v);
            const size_t idx = ((size_t)bh * SEQ + n) * DH + d;
            khg[idx] = (unsigned short)(u & 0xFFFFu);
            klg[idx] = (unsigned short)(u >> 16);
          } else {
            const unsigned int u = split2u(v * C_F);
            const size_t idx = ((size_t)bh * DH + d) * SEQ + n;
            vthg[idx] = (unsigned short)(u & 0xFFFFu);
            vtlg[idx] = (unsigned short)(u >> 16);
          }
        }
      }
  } else {
#pragma unroll
    for (int j = 0; j < 4; ++j) {
      const int gcol = bn + wc * 64 + j * 16 + lr;
      const float bg = (bias_m[gcol] > 0.f) ? bias[gcol] : 0.f;
#pragma unroll
      for (int i = 0; i < 4; ++i)
#pragma unroll
        for (int r = 0; r < 4; ++r) {
          const int grow = bm + wr * 64 + i * 16 + lg * 4 + r;
          oo[(size_t)grow * N + gcol] = acc[i][j][r] * C_F + bg;
        }
    }
  }
}

// ---------------------------------------------------------------------------
// Flash attention v3: XOR-swizzled LDS (T2) + async-stage split (T14).
// LDS arrays are [64 rows][64 shorts] (128 B rows); every 16B chunk is placed
// at chunk^(row&7) -> conflict-free b128 reads. P reuses Kh/Kl after QK^T.
// Next K/V tile is loaded into registers right after the LDS store, hiding
// HBM latency under QK^T+softmax+PV.
// ---------------------------------------------------------------------------
__global__ __launch_bounds__(256) void attn_mfma(
    const unsigned int* __restrict__ qpk, const unsigned short* __restrict__ khg,
    const unsigned short* __restrict__ klg,
    const unsigned short* __restrict__ vthg,
    const unsigned short* __restrict__ vtlg, unsigned int* __restrict__ aopk) {
  __shared__ unsigned short Kh[64 * 64];  // K phase: K hi; P phase: P hi
  __shared__ unsigned short Kl[64 * 64];  // K phase: K lo; P phase: P lo
  __shared__ unsigned short Vh[64 * 64];
  __shared__ unsigned short Vl[64 * 64];

  const int tid = threadIdx.x;
  const int l = tid & 63;
  const int w = tid >> 6;
  const int lr = l & 15, lg = l >> 4;
  const int qt = blockIdx.x;
  const int bh = blockIdx.y;

  // Q fragments for this wave's 16 rows (pre-scaled, packed hi|lo)
  bf16x8 qh[2], ql[2];
  const int q0 = qt * 64 + w * 16;
  const unsigned int* qrow = &qpk[((size_t)bh * SEQ + q0 + lr) * DH];
#pragma unroll
  for (int s = 0; s < 2; ++s) {
    const uint4 u0 = *(const uint4*)&qrow[s * 32 + lg * 8];
    const uint4 u1 = *(const uint4*)&qrow[s * 32 + lg * 8 + 4];
    bf16x8 h, lo;
    h[0] = (short)(u0.x & 0xFFFFu); lo[0] = (short)(u0.x >> 16);
    h[1] = (short)(u0.y & 0xFFFFu); lo[1] = (short)(u0.y >> 16);
    h[2] = (short)(u0.z & 0xFFFFu); lo[2] = (short)(u0.z >> 16);
    h[3] = (short)(u0.w & 0xFFFFu); lo[3] = (short)(u0.w >> 16);
    h[4] = (short)(u1.x & 0xFFFFu); lo[4] = (short)(u1.x >> 16);
    h[5] = (short)(u1.y & 0xFFFFu); lo[5] = (short)(u1.y >> 16);
    h[6] = (short)(u1.z & 0xFFFFu); lo[6] = (short)(u1.z >> 16);
    h[7] = (short)(u1.w & 0xFFFFu); lo[7] = (short)(u1.w >> 16);
    qh[s] = h;
    ql[s] = lo;
  }

  // staging: thread covers chunks (sr0, sc) and (sr0+32, sc)
  const int sr0 = tid >> 3, sc = tid & 7;
  const int sr1 = sr0 + 32;
  const int so0 = sr0 * 64 + ((sc ^ (sr0 & 7)) << 3);  // swizzled LDS offsets
  const int so1 = sr1 * 64 + ((sc ^ (sr1 & 7)) << 3);  // (sr1&7 == sr0&7)
  uint4 rk0h, rk1h, rk0l, rk1l, rv0h, rv1h, rv0l, rv1l;

#define LOAD_TILE(KT)                                                        \
  do {                                                                       \
    const size_t k0 = ((size_t)bh * SEQ + (KT)*64 + sr0) * DH + sc * 8;      \
    const size_t k1 = ((size_t)bh * SEQ + (KT)*64 + sr1) * DH + sc * 8;      \
    const size_t v0 = ((size_t)bh * DH + sr0) * SEQ + (KT)*64 + sc * 8;      \
    const size_t v1 = ((size_t)bh * DH + sr1) * SEQ + (KT)*64 + sc * 8;      \
    rk0h = *(const uint4*)&khg[k0];                                          \
    rk1h = *(const uint4*)&khg[k1];                                          \
    rk0l = *(const uint4*)&klg[k0];                                          \
    rk1l = *(const uint4*)&klg[k1];                                          \
    rv0h = *(const uint4*)&vthg[v0];                                         \
    rv1h = *(const uint4*)&vthg[v1];                                         \
    rv0l = *(const uint4*)&vtlg[v0];                                         \
    rv1l = *(const uint4*)&vtlg[v1];                                         \
  } while (0)

  f32x4 oacc[4];
  float m_i[4], l_i[4];
#pragma unroll
  for (int dt = 0; dt < 4; ++dt)
#pragma unroll
    for (int r = 0; r < 4; ++r) oacc[dt][r] = 0.f;
#pragma unroll
  for (int r = 0; r < 4; ++r) {
    m_i[r] = -1e30f;
    l_i[r] = 0.f;
  }

  LOAD_TILE(0);

  for (int kt = 0; kt < SEQ / 64; ++kt) {
    __syncthreads();  // prev iter's PV reads (P in Kh/Kl, V) complete
    // write staged registers -> LDS (swizzled)
    *(uint4*)&Kh[so0] = rk0h;
    *(uint4*)&Kh[so1] = rk1h;
    *(uint4*)&Kl[so0] = rk0l;
    *(uint4*)&Kl[so1] = rk1l;
    *(uint4*)&Vh[so0] = rv0h;
    *(uint4*)&Vh[so1] = rv1h;
    *(uint4*)&Vl[so0] = rv0l;
    *(uint4*)&Vl[so1] = rv1l;
    // issue next tile's loads now; latency hides under compute below (T14)
    if (kt + 1 < SEQ / 64) LOAD_TILE(kt + 1);
    __syncthreads();  // K/V tile visible

    // S = Q.K^T, 4 col-tiles, 3 passes
    f32x4 sacc[4];
#pragma unroll
    for (int ct = 0; ct < 4; ++ct)
#pragma unroll
      for (int r = 0; r < 4; ++r) sacc[ct][r] = 0.f;
#pragma unroll
    for (int ct = 0; ct < 4; ++ct)
#pragma unroll
      for (int s = 0; s < 2; ++s) {
        const int off = (ct * 16 + lr) * 64 + (((s * 4 + lg) ^ (lr & 7)) << 3);
        const bf16x8 kh = *(const bf16x8*)&Kh[off];
        const bf16x8 kl = *(const bf16x8*)&Kl[off];
        sacc[ct] = MFMA16(qh[s], kh, sacc[ct], 0, 0, 0);
        sacc[ct] = MFMA16(qh[s], kl, sacc[ct], 0, 0, 0);
        sacc[ct] = MFMA16(ql[s], kh, sacc[ct], 0, 0, 0);
      }

    // online softmax (rows lg*4+r; reduce across the 16 lanes of group lg)
    float ps[4][4], alpha[4];
#pragma unroll
    for (int r = 0; r < 4; ++r) {
      float mx = fmaxf(fmaxf(sacc[0][r], sacc[1][r]),
                       fmaxf(sacc[2][r], sacc[3][r]));
#pragma unroll
      for (int off = 1; off < 16; off <<= 1) mx = fmaxf(mx, __shfl_xor(mx, off));
      const float mn = fmaxf(m_i[r], mx);
      alpha[r] = __expf(m_i[r] - mn);
      float rs = 0.f;
#pragma unroll
      for (int ct = 0; ct < 4; ++ct) {
        ps[ct][r] = __expf(sacc[ct][r] - mn);
        rs += ps[ct][r];
      }
#pragma unroll
      for (int off = 1; off < 16; off <<= 1) rs += __shfl_xor(rs, off);
      l_i[r] = l_i[r] * alpha[r] + rs;
      m_i[r] = mn;
    }

    // rescale O (VALU, before the barrier)
#pragma unroll
    for (int dt = 0; dt < 4; ++dt)
#pragma unroll
      for (int r = 0; r < 4; ++r) oacc[dt][r] *= alpha[r];

    __syncthreads();  // ALL waves done reading K -> safe to overwrite with P

    // write P (hi/lo) transposed into this wave's 16-row slice of Kh/Kl
#pragma unroll
    for (int ct = 0; ct < 4; ++ct)
#pragma unroll
      for (int r = 0; r < 4; ++r) {
        const unsigned short h = f2bf(ps[ct][r]);
        const int qr = w * 16 + lg * 4 + r;
        const int pchunk = ct * 2 + (lr >> 3);
        const int pidx =
            qr * 64 + ((pchunk ^ ((lg * 4 + r) & 7)) << 3) + (lr & 7);
        Kh[pidx] = h;
        Kl[pidx] = f2bf(ps[ct][r] - bf2f(h));
      }

    // O += P.V  (3 passes; wave reads only its own slice -> program order ok)
#pragma unroll
    for (int s = 0; s < 2; ++s) {
      const int poff = (w * 16 + lr) * 64 + (((s * 4 + lg) ^ (lr & 7)) << 3);
      const bf16x8 ph = *(const bf16x8*)&Kh[poff];
      const bf16x8 pl = *(const bf16x8*)&Kl[poff];
#pragma unroll
      for (int dt = 0; dt < 4; ++dt) {
        const int off = (dt * 16 + lr) * 64 + (((s * 4 + lg) ^ (lr & 7)) << 3);
        const bf16x8 vh = *(const bf16x8*)&Vh[off];
        const bf16x8 vl = *(const bf16x8*)&Vl[off];
        oacc[dt] = MFMA16(ph, vh, oacc[dt], 0, 0, 0);
        oacc[dt] = MFMA16(ph, vl, oacc[dt], 0, 0, 0);
        oacc[dt] = MFMA16(pl, vh, oacc[dt], 0, 0, 0);
      }
    }
  }
#undef LOAD_TILE

  // epilogue: O / l_i -> aopk [b][n][h*64+d], packed-split u32
  const int b = bh >> 4, hh = bh & 15;
#pragma unroll
  for (int r = 0; r < 4; ++r) {
    const float inv = 1.f / l_i[r];
    const int n = qt * 64 + w * 16 + lg * 4 + r;
#pragma unroll
    for (int dt = 0; dt < 4; ++dt)
      aopk[((size_t)(b * SEQ + n)) * KDIM + hh * DH + dt * 16 + lr] =
          split2u(oacc[dt][r] * inv);
  }
}

// ---------------------------------------------------------------------------
extern "C" void kernel_launch(void* const* d_in, const int* in_sizes, int n_in,
                              void* d_out, int out_size, void* d_ws,
                              size_t ws_size, hipStream_t stream) {
  const float* x = (const float*)d_in[0];
  const float* qkvw = (const float*)d_in[1];
  const float* qkvm = (const float*)d_in[2];
  const float* outw = (const float*)d_in[3];
  const float* outm = (const float*)d_in[4];
  const float* ob = (const float*)d_in[5];
  const float* obm = (const float*)d_in[6];
  float* out = (float*)d_out;

  // ws (64 MB):
  //  [ 0,16M) qpk  u32 packed-split q   (live: gemm0 -> attn);  so aliases after
  //  [16,24M) khg  bf16 hi K            (live: gemm0 -> attn)
  //  [24,32M) klg  bf16 lo K
  //  [32,40M) vthg bf16 hi V^T
  //  [40,48M) vtlg bf16 lo V^T
  //  [48,64M) aopk u32 packed-split attn-out (live: attn -> gemm1);
  //           sq (6MB) aliases this region before attn writes it.
  char* base = (char*)d_ws;
  unsigned int* qpk = (unsigned int*)base;
  unsigned short* khg = (unsigned short*)(base + (16u << 20));
  unsigned short* klg = (unsigned short*)(base + (24u << 20));
  unsigned short* vthg = (unsigned short*)(base + (32u << 20));
  unsigned short* vtlg = (unsigned short*)(base + (40u << 20));
  unsigned int* aopk = (unsigned int*)(base + (48u << 20));
  unsigned short* sq = (unsigned short*)aopk;  // dead before aopk written
  unsigned short* so = (unsigned short*)qpk;   // written after qpk dead

  sign_gate<<<dim3(N3 * KDIM / 4 / 256), 256, 0, stream>>>(qkvw, qkvm, sq,
                                                           N3 * KDIM / 4);
  gemm_mfma<0><<<dim3(N3 / 128, MROWS / 128), 256, 0, stream>>>(
      x, nullptr, sq, nullptr, nullptr, qpk, khg, klg, vthg, vtlg, nullptr,
      MROWS, N3, KDIM);
  attn_mfma<<<dim3(SEQ / 64, 32), 256, 0, stream>>>(qpk, khg, klg, vthg, vtlg,
                                                    aopk);
  sign_gate<<<dim3(KDIM * KDIM / 4 / 256), 256, 0, stream>>>(outw, outm, so,
                                                             KDIM * KDIM / 4);
  gemm_mfma<1><<<dim3(KDIM / 128, MROWS / 128), 256, 0, stream>>>(
      nullptr, aopk, so, ob, obm, nullptr, nullptr, nullptr, nullptr, nullptr,
      out, MROWS, KDIM, KDIM);
}

// Round 11
// 402.444 us; speedup vs baseline: 1.1735x; 1.1735x over previous
//
#include <hip/hip_runtime.h>

#define HEADS 16
#define DH 64
#define SEQ 2048
#define MROWS 4096          // b*n = 2*2048
#define KDIM 1024
#define N3 3072

// e * sqrt(1/1024)
#define C_D (2.718281828459045 * 0.03125)
#define C_F ((float)C_D)
#define QSCALE ((float)(C_D * C_D / 32.0))

typedef __attribute__((ext_vector_type(8))) short bf16x8;
typedef __attribute__((ext_vector_type(4))) short s16x4;
typedef __attribute__((ext_vector_type(4))) float f32x4;
#define MFMA16 __builtin_amdgcn_mfma_f32_16x16x32_bf16

__device__ __forceinline__ unsigned short f2bf(float f) {
  unsigned int u = __float_as_uint(f);
  unsigned int r = u + 0x7FFFu + ((u >> 16) & 1u);  // RNE
  return (unsigned short)(r >> 16);
}
__device__ __forceinline__ float bf2f(unsigned short h) {
  return __uint_as_float(((unsigned int)h) << 16);
}
// hi bf16 in bits [15:0], lo bf16 in bits [31:16]
__device__ __forceinline__ unsigned int split2u(float v) {
  const unsigned short hh = f2bf(v);
  const unsigned short ll = f2bf(v - bf2f(hh));
  return (unsigned int)hh | ((unsigned int)ll << 16);
}

// ---------------------------------------------------------------------------
// signs: s = gate(m) ? sign(w) : 0, in bf16 {±1, 0} (exact)
// ---------------------------------------------------------------------------
__global__ __launch_bounds__(256) void sign_gate(const float* __restrict__ w,
                                                 const float* __restrict__ m,
                                                 unsigned short* __restrict__ s,
                                                 int n4) {
  const int i = blockIdx.x * 256 + threadIdx.x;
  if (i >= n4) return;
  const float4 wv = ((const float4*)w)[i];
  const float4 mv = ((const float4*)m)[i];
  s16x4 r;
  r[0] = (mv.x > 0.f) ? (wv.x > 0.f ? (short)0x3F80 : (short)0xBF80) : (short)0;
  r[1] = (mv.y > 0.f) ? (wv.y > 0.f ? (short)0x3F80 : (short)0xBF80) : (short)0;
  r[2] = (mv.z > 0.f) ? (wv.z > 0.f ? (short)0x3F80 : (short)0xBF80) : (short)0;
  r[3] = (mv.w > 0.f) ? (wv.w > 0.f ? (short)0x3F80 : (short)0xBF80) : (short)0;
  ((s16x4*)s)[i] = r;
}

// ---------------------------------------------------------------------------
// Split-bf16 MFMA GEMM (unchanged): C = (A_hi + A_lo) @ Bsgn^T.
// ---------------------------------------------------------------------------
template <int MODE>
__global__ __launch_bounds__(256) void gemm_mfma(
    const float* __restrict__ Af, const unsigned int* __restrict__ Apk,
    const unsigned short* __restrict__ Bsgn, const float* __restrict__ bias,
    const float* __restrict__ bias_m, unsigned int* __restrict__ qpk,
    unsigned short* __restrict__ khg, unsigned short* __restrict__ klg,
    unsigned short* __restrict__ vthg, unsigned short* __restrict__ vtlg,
    float* __restrict__ oo, int M, int N, int K) {
  __shared__ unsigned short Ah[128 * 40];
  __shared__ unsigned short Al[128 * 40];
  __shared__ unsigned short Bt[128 * 40];
  const int tid = threadIdx.x;
  const int l = tid & 63;
  const int w = tid >> 6;
  const int lr = l & 15, lg = l >> 4;
  const int wr = w >> 1, wc = w & 1;
  const int bm = blockIdx.y * 128, bn = blockIdx.x * 128;

  f32x4 acc[4][4];
#pragma unroll
  for (int i = 0; i < 4; ++i)
#pragma unroll
    for (int j = 0; j < 4; ++j)
#pragma unroll
      for (int r = 0; r < 4; ++r) acc[i][j][r] = 0.f;

  for (int k0 = 0; k0 < K; k0 += 32) {
    __syncthreads();
    // ---- stage A (128x32) ----
#pragma unroll
    for (int p = 0; p < 4; ++p) {
      const int ch = tid + p * 256;
      const int r = ch >> 3, c = ch & 7;
      s16x4 hv, lv;
      if (MODE == 0) {
        const float4 f = *(const float4*)&Af[(size_t)(bm + r) * K + k0 + c * 4];
        const unsigned int p0 = split2u(f.x), p1 = split2u(f.y),
                           p2 = split2u(f.z), p3 = split2u(f.w);
        hv[0] = (short)(p0 & 0xFFFFu); lv[0] = (short)(p0 >> 16);
        hv[1] = (short)(p1 & 0xFFFFu); lv[1] = (short)(p1 >> 16);
        hv[2] = (short)(p2 & 0xFFFFu); lv[2] = (short)(p2 >> 16);
        hv[3] = (short)(p3 & 0xFFFFu); lv[3] = (short)(p3 >> 16);
      } else {
        const uint4 u = *(const uint4*)&Apk[(size_t)(bm + r) * K + k0 + c * 4];
        hv[0] = (short)(u.x & 0xFFFFu); lv[0] = (short)(u.x >> 16);
        hv[1] = (short)(u.y & 0xFFFFu); lv[1] = (short)(u.y >> 16);
        hv[2] = (short)(u.z & 0xFFFFu); lv[2] = (short)(u.z >> 16);
        hv[3] = (short)(u.w & 0xFFFFu); lv[3] = (short)(u.w >> 16);
      }
      *(s16x4*)&Ah[r * 40 + c * 4] = hv;
      *(s16x4*)&Al[r * 40 + c * 4] = lv;
    }
    // ---- stage B signs ----
#pragma unroll
    for (int p = 0; p < 2; ++p) {
      const int ch = tid + p * 256;
      const int r = ch >> 2, c = ch & 3;
      const uint4 u = *(const uint4*)&Bsgn[(size_t)(bn + r) * K + k0 + c * 8];
      *(uint4*)&Bt[r * 40 + c * 8] = u;
    }
    __syncthreads();

    bf16x8 af[4], alf[4], bfr[4];
#pragma unroll
    for (int i = 0; i < 4; ++i) {
      const int row = wr * 64 + i * 16 + lr;
      af[i] = *(const bf16x8*)&Ah[row * 40 + lg * 8];
      alf[i] = *(const bf16x8*)&Al[row * 40 + lg * 8];
    }
#pragma unroll
    for (int j = 0; j < 4; ++j)
      bfr[j] = *(const bf16x8*)&Bt[(wc * 64 + j * 16 + lr) * 40 + lg * 8];
#pragma unroll
    for (int i = 0; i < 4; ++i)
#pragma unroll
      for (int j = 0; j < 4; ++j) {
        acc[i][j] = MFMA16(af[i], bfr[j], acc[i][j], 0, 0, 0);
        acc[i][j] = MFMA16(alf[i], bfr[j], acc[i][j], 0, 0, 0);
      }
  }

  // ---- epilogue ----
  if (MODE == 0) {
    const int part = bn >> 10;      // 0=q, 1=k, 2=v
    const int rembase = bn & 1023;  // within part
#pragma unroll
    for (int i = 0; i < 4; ++i)
#pragma unroll
      for (int j = 0; j < 4; ++j) {
        const int gcol = rembase + wc * 64 + j * 16 + lr;
        const int h = gcol >> 6, d = gcol & 63;
#pragma unroll
        for (int r = 0; r < 4; ++r) {
          const int grow = bm + wr * 64 + i * 16 + lg * 4 + r;
          const int b = grow >> 11, n = grow & 2047;
          const int bh = b * HEADS + h;
          const float v = acc[i][j][r];
          if (part == 0) {
            qpk[((size_t)bh * SEQ + n) * DH + d] = split2u(v * QSCALE);
          } else if (part == 1) {
            const unsigned int u = split2u(v);
            const size_t idx = ((size_t)bh * SEQ + n) * DH + d;
            khg[idx] = (unsigned short)(u & 0xFFFFu);
            klg[idx] = (unsigned short)(u >> 16);
          } else {
            const unsigned int u = split2u(v * C_F);
            const size_t idx = ((size_t)bh * DH + d) * SEQ + n;
            vthg[idx] = (unsigned short)(u & 0xFFFFu);
            vtlg[idx] = (unsigned short)(u >> 16);
          }
        }
      }
  } else {
#pragma unroll
    for (int j = 0; j < 4; ++j) {
      const int gcol = bn + wc * 64 + j * 16 + lr;
      const float bg = (bias_m[gcol] > 0.f) ? bias[gcol] : 0.f;
#pragma unroll
      for (int i = 0; i < 4; ++i)
#pragma unroll
        for (int r = 0; r < 4; ++r) {
          const int grow = bm + wr * 64 + i * 16 + lg * 4 + r;
          oo[(size_t)grow * N + gcol] = acc[i][j][r] * C_F + bg;
        }
    }
  }
}

// ---------------------------------------------------------------------------
// Flash attention v4: XOR-swizzled LDS (T2, conflicts=0 verified r9) with
// DIRECT global->LDS staging (T14 reg-staging reverted: it cost +48 VGPR and
// dropped occupancy 26%->11%, r9). LDS [64][64] shorts, chunk' = chunk^(row&7).
// P reuses Kh/Kl after QK^T (barrier).
// ---------------------------------------------------------------------------
__global__ __launch_bounds__(256) void attn_mfma(
    const unsigned int* __restrict__ qpk, const unsigned short* __restrict__ khg,
    const unsigned short* __restrict__ klg,
    const unsigned short* __restrict__ vthg,
    const unsigned short* __restrict__ vtlg, unsigned int* __restrict__ aopk) {
  __shared__ unsigned short Kh[64 * 64];  // K phase: K hi; P phase: P hi
  __shared__ unsigned short Kl[64 * 64];  // K phase: K lo; P phase: P lo
  __shared__ unsigned short Vh[64 * 64];
  __shared__ unsigned short Vl[64 * 64];

  const int tid = threadIdx.x;
  const int l = tid & 63;
  const int w = tid >> 6;
  const int lr = l & 15, lg = l >> 4;
  const int qt = blockIdx.x;
  const int bh = blockIdx.y;

  // Q fragments for this wave's 16 rows (pre-scaled, packed hi|lo)
  bf16x8 qh[2], ql[2];
  const int q0 = qt * 64 + w * 16;
  const unsigned int* qrow = &qpk[((size_t)bh * SEQ + q0 + lr) * DH];
#pragma unroll
  for (int s = 0; s < 2; ++s) {
    const uint4 u0 = *(const uint4*)&qrow[s * 32 + lg * 8];
    const uint4 u1 = *(const uint4*)&qrow[s * 32 + lg * 8 + 4];
    bf16x8 h, lo;
    h[0] = (short)(u0.x & 0xFFFFu); lo[0] = (short)(u0.x >> 16);
    h[1] = (short)(u0.y & 0xFFFFu); lo[1] = (short)(u0.y >> 16);
    h[2] = (short)(u0.z & 0xFFFFu); lo[2] = (short)(u0.z >> 16);
    h[3] = (short)(u0.w & 0xFFFFu); lo[3] = (short)(u0.w >> 16);
    h[4] = (short)(u1.x & 0xFFFFu); lo[4] = (short)(u1.x >> 16);
    h[5] = (short)(u1.y & 0xFFFFu); lo[5] = (short)(u1.y >> 16);
    h[6] = (short)(u1.z & 0xFFFFu); lo[6] = (short)(u1.z >> 16);
    h[7] = (short)(u1.w & 0xFFFFu); lo[7] = (short)(u1.w >> 16);
    qh[s] = h;
    ql[s] = lo;
  }

  // staging geometry: thread covers chunks (sr0, sc) and (sr0+32, sc)
  const int sr0 = tid >> 3, sc = tid & 7;
  const int sr1 = sr0 + 32;
  const int so0 = sr0 * 64 + ((sc ^ (sr0 & 7)) << 3);  // swizzled LDS offsets
  const int so1 = sr1 * 64 + ((sc ^ (sr1 & 7)) << 3);  // (sr1&7 == sr0&7)

  f32x4 oacc[4];
  float m_i[4], l_i[4];
#pragma unroll
  for (int dt = 0; dt < 4; ++dt)
#pragma unroll
    for (int r = 0; r < 4; ++r) oacc[dt][r] = 0.f;
#pragma unroll
  for (int r = 0; r < 4; ++r) {
    m_i[r] = -1e30f;
    l_i[r] = 0.f;
  }

  for (int kt = 0; kt < SEQ / 64; ++kt) {
    __syncthreads();  // prev iter's PV reads (P in Kh/Kl, V) complete
    // direct global -> LDS staging (swizzled stores)
    {
      const size_t k0 = ((size_t)bh * SEQ + kt * 64 + sr0) * DH + sc * 8;
      const size_t k1 = ((size_t)bh * SEQ + kt * 64 + sr1) * DH + sc * 8;
      const size_t v0 = ((size_t)bh * DH + sr0) * SEQ + kt * 64 + sc * 8;
      const size_t v1 = ((size_t)bh * DH + sr1) * SEQ + kt * 64 + sc * 8;
      *(uint4*)&Kh[so0] = *(const uint4*)&khg[k0];
      *(uint4*)&Kh[so1] = *(const uint4*)&khg[k1];
      *(uint4*)&Kl[so0] = *(const uint4*)&klg[k0];
      *(uint4*)&Kl[so1] = *(const uint4*)&klg[k1];
      *(uint4*)&Vh[so0] = *(const uint4*)&vthg[v0];
      *(uint4*)&Vh[so1] = *(const uint4*)&vthg[v1];
      *(uint4*)&Vl[so0] = *(const uint4*)&vtlg[v0];
      *(uint4*)&Vl[so1] = *(const uint4*)&vtlg[v1];
    }
    __syncthreads();  // K/V tile visible

    // S = Q.K^T, 4 col-tiles, 3 passes (swizzled reads)
    f32x4 sacc[4];
#pragma unroll
    for (int ct = 0; ct < 4; ++ct)
#pragma unroll
      for (int r = 0; r < 4; ++r) sacc[ct][r] = 0.f;
#pragma unroll
    for (int ct = 0; ct < 4; ++ct)
#pragma unroll
      for (int s = 0; s < 2; ++s) {
        const int off = (ct * 16 + lr) * 64 + (((s * 4 + lg) ^ (lr & 7)) << 3);
        const bf16x8 kh = *(const bf16x8*)&Kh[off];
        const bf16x8 kl = *(const bf16x8*)&Kl[off];
        sacc[ct] = MFMA16(qh[s], kh, sacc[ct], 0, 0, 0);
        sacc[ct] = MFMA16(qh[s], kl, sacc[ct], 0, 0, 0);
        sacc[ct] = MFMA16(ql[s], kh, sacc[ct], 0, 0, 0);
      }

    // online softmax (rows lg*4+r; reduce across the 16 lanes of group lg)
    float ps[4][4], alpha[4];
#pragma unroll
    for (int r = 0; r < 4; ++r) {
      float mx = fmaxf(fmaxf(sacc[0][r], sacc[1][r]),
                       fmaxf(sacc[2][r], sacc[3][r]));
#pragma unroll
      for (int off = 1; off < 16; off <<= 1) mx = fmaxf(mx, __shfl_xor(mx, off));
      const float mn = fmaxf(m_i[r], mx);
      alpha[r] = __expf(m_i[r] - mn);
      float rs = 0.f;
#pragma unroll
      for (int ct = 0; ct < 4; ++ct) {
        ps[ct][r] = __expf(sacc[ct][r] - mn);
        rs += ps[ct][r];
      }
#pragma unroll
      for (int off = 1; off < 16; off <<= 1) rs += __shfl_xor(rs, off);
      l_i[r] = l_i[r] * alpha[r] + rs;
      m_i[r] = mn;
    }

    // rescale O (VALU, before the barrier)
#pragma unroll
    for (int dt = 0; dt < 4; ++dt)
#pragma unroll
      for (int r = 0; r < 4; ++r) oacc[dt][r] *= alpha[r];

    __syncthreads();  // ALL waves done reading K -> safe to overwrite with P

    // write P (hi/lo) transposed into this wave's 16-row slice of Kh/Kl
#pragma unroll
    for (int ct = 0; ct < 4; ++ct)
#pragma unroll
      for (int r = 0; r < 4; ++r) {
        const unsigned short h = f2bf(ps[ct][r]);
        const int qr = w * 16 + lg * 4 + r;
        const int pchunk = ct * 2 + (lr >> 3);
        const int pidx =
            qr * 64 + ((pchunk ^ ((lg * 4 + r) & 7)) << 3) + (lr & 7);
        Kh[pidx] = h;
        Kl[pidx] = f2bf(ps[ct][r] - bf2f(h));
      }

    // O += P.V  (3 passes; wave reads only its own slice -> program order ok)
#pragma unroll
    for (int s = 0; s < 2; ++s) {
      const int poff = (w * 16 + lr) * 64 + (((s * 4 + lg) ^ (lr & 7)) << 3);
      const bf16x8 ph = *(const bf16x8*)&Kh[poff];
      const bf16x8 pl = *(const bf16x8*)&Kl[poff];
#pragma unroll
      for (int dt = 0; dt < 4; ++dt) {
        const int off = (dt * 16 + lr) * 64 + (((s * 4 + lg) ^ (lr & 7)) << 3);
        const bf16x8 vh = *(const bf16x8*)&Vh[off];
        const bf16x8 vl = *(const bf16x8*)&Vl[off];
        oacc[dt] = MFMA16(ph, vh, oacc[dt], 0, 0, 0);
        oacc[dt] = MFMA16(ph, vl, oacc[dt], 0, 0, 0);
        oacc[dt] = MFMA16(pl, vh, oacc[dt], 0, 0, 0);
      }
    }
  }

  // epilogue: O / l_i -> aopk [b][n][h*64+d], packed-split u32
  const int b = bh >> 4, hh = bh & 15;
#pragma unroll
  for (int r = 0; r < 4; ++r) {
    const float inv = 1.f / l_i[r];
    const int n = qt * 64 + w * 16 + lg * 4 + r;
#pragma unroll
    for (int dt = 0; dt < 4; ++dt)
      aopk[((size_t)(b * SEQ + n)) * KDIM + hh * DH + dt * 16 + lr] =
          split2u(oacc[dt][r] * inv);
  }
}

// ---------------------------------------------------------------------------
extern "C" void kernel_launch(void* const* d_in, const int* in_sizes, int n_in,
                              void* d_out, int out_size, void* d_ws,
                              size_t ws_size, hipStream_t stream) {
  const float* x = (const float*)d_in[0];
  const float* qkvw = (const float*)d_in[1];
  const float* qkvm = (const float*)d_in[2];
  const float* outw = (const float*)d_in[3];
  const float* outm = (const float*)d_in[4];
  const float* ob = (const float*)d_in[5];
  const float* obm = (const float*)d_in[6];
  float* out = (float*)d_out;

  // ws (64 MB):
  //  [ 0,16M) qpk  u32 packed-split q   (live: gemm0 -> attn);  so aliases after
  //  [16,24M) khg  bf16 hi K            (live: gemm0 -> attn)
  //  [24,32M) klg  bf16 lo K
  //  [32,40M) vthg bf16 hi V^T
  //  [40,48M) vtlg bf16 lo V^T
  //  [48,64M) aopk u32 packed-split attn-out (live: attn -> gemm1);
  //           sq (6MB) aliases this region before attn writes it.
  char* base = (char*)d_ws;
  unsigned int* qpk = (unsigned int*)base;
  unsigned short* khg = (unsigned short*)(base + (16u << 20));
  unsigned short* klg = (unsigned short*)(base + (24u << 20));
  unsigned short* vthg = (unsigned short*)(base + (32u << 20));
  unsigned short* vtlg = (unsigned short*)(base + (40u << 20));
  unsigned int* aopk = (unsigned int*)(base + (48u << 20));
  unsigned short* sq = (unsigned short*)aopk;  // dead before aopk written
  unsigned short* so = (unsigned short*)qpk;   // written after qpk dead

  sign_gate<<<dim3(N3 * KDIM / 4 / 256), 256, 0, stream>>>(qkvw, qkvm, sq,
                                                           N3 * KDIM / 4);
  gemm_mfma<0><<<dim3(N3 / 128, MROWS / 128), 256, 0, stream>>>(
      x, nullptr, sq, nullptr, nullptr, qpk, khg, klg, vthg, vtlg, nullptr,
      MROWS, N3, KDIM);
  attn_mfma<<<dim3(SEQ / 64, 32), 256, 0, stream>>>(qpk, khg, klg, vthg, vtlg,
                                                    aopk);
  sign_gate<<<dim3(KDIM * KDIM / 4 / 256), 256, 0, stream>>>(outw, outm, so,
                                                             KDIM * KDIM / 4);
  gemm_mfma<1><<<dim3(KDIM / 128, MROWS / 128), 256, 0, stream>>>(
      nullptr, aopk, so, ob, obm, nullptr, nullptr, nullptr, nullptr, nullptr,
      out, MROWS, KDIM, KDIM);
}